// Round 4
// baseline (376.296 us; speedup 1.0000x reference)
//
#include <hip/hip_runtime.h>

// Chain of 9 Linear layers, no activation => collapse to one affine map.
// dims: 784 -> 69 -> 31 -> 10 -> ... -> 10
//
//   P1 (1 block):   S8 = W8*...*W1 [10,69], beff = S8 @ b0 + collapsed bias
//   P2 (31 blocks): Wt[j*10+o] = sum_k S8[o][k] * W0[k][j]   ([784][10], o fastest)
//   MAIN: out[b][o] = sum_j x[b][j]*Wt[j*10+o] + beff[o]
//
// MAIN (R4): R3's 4-wave row split + weights in LDS.
//   R3's weight path asked for 280 wave-uniform floats per unrolled group —
//   exceeds the 102-SGPR budget, so the compiler serialized s_load bursts /
//   demoted to VMEM. Now: stage Wt (31.4 KB) into LDS once per block, read as
//   broadcast ds_read_b128 (same addr across lanes: conflict-free). x path
//   unchanged: lane=row, wave q covers j in [q*196,(q+1)*196), register
//   ping-pong prefetch, zero main-loop barriers.

__global__ void prep_collapse(
    const float* __restrict__ W1, const float* __restrict__ b1,
    const float* __restrict__ W2, const float* __restrict__ b2,
    const float* __restrict__ W3, const float* __restrict__ b3,
    const float* __restrict__ W4, const float* __restrict__ b4,
    const float* __restrict__ W5, const float* __restrict__ b5,
    const float* __restrict__ W6, const float* __restrict__ b6,
    const float* __restrict__ W7, const float* __restrict__ b7,
    const float* __restrict__ W8, const float* __restrict__ b8,
    const float* __restrict__ b0,
    float* __restrict__ S8out, float* __restrict__ beff)
{
    __shared__ float Sa[31 * 69], Sb[31 * 69];
    __shared__ float da[31], db[31];
    const int t = threadIdx.x;
    const int nt = blockDim.x;

    for (int i = t; i < 31 * 69; i += nt) Sa[i] = W1[i];
    for (int i = t; i < 31; i += nt) da[i] = b1[i];
    __syncthreads();

    for (int i = t; i < 10 * 69; i += nt) {
        int o = i / 69, c = i - o * 69;
        float s = 0.f;
        for (int k = 0; k < 31; k++) s += W2[o * 31 + k] * Sa[k * 69 + c];
        Sb[i] = s;
    }
    for (int i = t; i < 10; i += nt) {
        float s = b2[i];
        for (int k = 0; k < 31; k++) s += W2[i * 31 + k] * da[k];
        db[i] = s;
    }
    __syncthreads();

    const float* Wk[6] = { W3, W4, W5, W6, W7, W8 };
    const float* bk[6] = { b3, b4, b5, b6, b7, b8 };
    int src = 1;  // runtime ternaries: gfx950 rejects arrays of LDS pointers
    for (int st = 0; st < 6; st++) {
        const float* W = Wk[st];
        const float* bb = bk[st];
        float* S  = src ? Sb : Sa;
        float* D  = src ? Sa : Sb;
        float* dd = src ? db : da;
        float* dn = src ? da : db;
        for (int i = t; i < 10 * 69; i += nt) {
            int o = i / 69, c = i - o * 69;
            float s = 0.f;
            for (int k = 0; k < 10; k++) s += W[o * 10 + k] * S[k * 69 + c];
            D[i] = s;
        }
        for (int i = t; i < 10; i += nt) {
            float s = bb[i];
            for (int k = 0; k < 10; k++) s += W[i * 10 + k] * dd[k];
            dn[i] = s;
        }
        __syncthreads();
        src ^= 1;
    }

    float* S  = src ? Sb : Sa;
    float* dd = src ? db : da;
    for (int i = t; i < 690; i += nt) S8out[i] = S[i];
    for (int i = t; i < 10; i += nt) {
        float s = dd[i];
        for (int k = 0; k < 69; k++) s += S[i * 69 + k] * b0[k];
        beff[i] = s;
    }
}

__global__ void prep_fold0(const float* __restrict__ W0,
                           const float* __restrict__ S8,
                           float* __restrict__ Wt)
{
    int idx = blockIdx.x * blockDim.x + threadIdx.x;  // o*784 + j
    if (idx >= 7840) return;
    int o = idx / 784, j = idx - o * 784;
    float s = 0.f;
    for (int k = 0; k < 69; k++) s += S8[o * 69 + k] * W0[k * 784 + j];
    Wt[j * 10 + o] = s;  // [784][10]
}

// ---- main ----

#define LOADG(dst, g)                                               \
    _Pragma("unroll")                                               \
    for (int i = 0; i < 7; i++)                                     \
        dst[i] = *(const float4*)(xp + (g) * 28 + i * 4);

// per float4 of x (4 j's): 10 broadcast ds_read_b128 -> 40 weight floats,
// then 40 FMAs. All indices constant after unroll -> registers.
#define COMP(src, g)                                                \
    _Pragma("unroll")                                               \
    for (int i = 0; i < 7; i++) {                                   \
        const int j0 = (g) * 28 + i * 4;                            \
        const float4* wv = (const float4*)(wq + j0 * 10);           \
        float w[40];                                                \
        _Pragma("unroll")                                           \
        for (int k = 0; k < 10; k++) {                              \
            float4 t4 = wv[k];                                      \
            w[4*k+0] = t4.x; w[4*k+1] = t4.y;                       \
            w[4*k+2] = t4.z; w[4*k+3] = t4.w;                       \
        }                                                           \
        _Pragma("unroll")                                           \
        for (int o = 0; o < 10; o++) acc[o] = fmaf(src[i].x, w[o],      acc[o]); \
        _Pragma("unroll")                                           \
        for (int o = 0; o < 10; o++) acc[o] = fmaf(src[i].y, w[10 + o], acc[o]); \
        _Pragma("unroll")                                           \
        for (int o = 0; o < 10; o++) acc[o] = fmaf(src[i].z, w[20 + o], acc[o]); \
        _Pragma("unroll")                                           \
        for (int o = 0; o < 10; o++) acc[o] = fmaf(src[i].w, w[30 + o], acc[o]); \
    }

__global__ __launch_bounds__(256, 4) void linear_main(
    const float* __restrict__ x, const float* __restrict__ Wt,
    const float* __restrict__ beff, float* __restrict__ out)
{
    __shared__ float ldsW[7840];        // Wt [784][10], 31.4 KB
    __shared__ float part[3 * 64 * 10]; // wave partials, 7.7 KB
    const int t = threadIdx.x;
    const int lane = t & 63;
    const int q = __builtin_amdgcn_readfirstlane(t >> 6);
    const long row = (long)blockIdx.x * 64 + lane;

    // stage all weights to LDS (1960 float4 / 256 threads)
    {
        const float4* wg = (const float4*)Wt;
        float4* wl = (float4*)ldsW;
        for (int i = t; i < 1960; i += 256) wl[i] = wg[i];
    }

    const float* xp = x + row * 784 + q * 196;   // per-lane
    const float* wq = ldsW + q * 1960;           // wave-uniform -> broadcast

    float acc[10];
#pragma unroll
    for (int o = 0; o < 10; o++) acc[o] = 0.f;

    float4 A[7], Bv[7];
    // issue first x prefetch before the staging barrier (independent of LDS)
    LOADG(A, 0)
    __syncthreads();

    LOADG(Bv, 1) COMP(A, 0)
    LOADG(A, 2)  COMP(Bv, 1)
    LOADG(Bv, 3) COMP(A, 2)
    LOADG(A, 4)  COMP(Bv, 3)
    LOADG(Bv, 5) COMP(A, 4)
    LOADG(A, 6)  COMP(Bv, 5)
    COMP(A, 6)

    // combine 4 wave-partials through LDS (one barrier)
    if (q != 0) {
#pragma unroll
        for (int o = 0; o < 10; o++) part[(q - 1) * 640 + lane * 10 + o] = acc[o];
    }
    __syncthreads();
    if (q == 0) {
#pragma unroll
        for (int w = 0; w < 3; w++)
#pragma unroll
            for (int o = 0; o < 10; o++) acc[o] += part[w * 640 + lane * 10 + o];
        float* op = out + row * 10;
#pragma unroll
        for (int o = 0; o < 10; o += 2)
            *(float2*)(op + o) = make_float2(acc[o] + beff[o], acc[o + 1] + beff[o + 1]);
    }
}

extern "C" void kernel_launch(void* const* d_in, const int* in_sizes, int n_in,
                              void* d_out, int out_size, void* d_ws, size_t ws_size,
                              hipStream_t stream) {
    const float* x  = (const float*)d_in[0];
    const float* W0 = (const float*)d_in[1];
    const float* b0 = (const float*)d_in[2];
    const float* W1 = (const float*)d_in[3];
    const float* b1 = (const float*)d_in[4];
    const float* W2 = (const float*)d_in[5];
    const float* b2 = (const float*)d_in[6];
    const float* W3 = (const float*)d_in[7];
    const float* b3 = (const float*)d_in[8];
    const float* W4 = (const float*)d_in[9];
    const float* b4 = (const float*)d_in[10];
    const float* W5 = (const float*)d_in[11];
    const float* b5 = (const float*)d_in[12];
    const float* W6 = (const float*)d_in[13];
    const float* b6 = (const float*)d_in[14];
    const float* W7 = (const float*)d_in[15];
    const float* b7 = (const float*)d_in[16];
    const float* W8 = (const float*)d_in[17];
    const float* b8 = (const float*)d_in[18];

    float* ws   = (float*)d_ws;
    float* Wt   = ws;            // 7840 floats: [784][10]
    float* beff = ws + 7840;     // 10 floats
    float* S8   = ws + 7856;     // 690 floats

    float* out = (float*)d_out;
    const int B = in_sizes[0] / 784;  // 65536

    prep_collapse<<<1, 256, 0, stream>>>(W1, b1, W2, b2, W3, b3, W4, b4,
                                         W5, b5, W6, b6, W7, b7, W8, b8,
                                         b0, S8, beff);
    prep_fold0<<<31, 256, 0, stream>>>(W0, S8, Wt);
    linear_main<<<B / 64, 256, 0, stream>>>(x, Wt, beff, out);
}